// Round 2
// baseline (421.030 us; speedup 1.0000x reference)
//
#include <hip/hip_runtime.h>
#include <hip/hip_bf16.h>
#include <stdint.h>

// Problem constants
#define BB 8
#define SS 1024
#define DD 512
#define MROWS (BB*SS)        // 8192
#define NEG_EPS 1e-9f
#define INV_S (1.0f/1024.0f)

typedef __attribute__((ext_vector_type(8))) __bf16 bf16x8;
typedef __attribute__((ext_vector_type(4))) __bf16 bf16x4;
typedef __attribute__((ext_vector_type(4))) float f32x4;

__device__ __forceinline__ void gload_lds16(const void* g, void* l) {
    __builtin_amdgcn_global_load_lds(
        (const __attribute__((address_space(1))) void*)g,
        (__attribute__((address_space(3))) void*)l,
        16, 0, 0);
}

// ============ K1: convert ctx -> bf16  AND  M = Wq^T @ Wk (bf16)  AND bias vecs ============
// grid: [0,2048) convert, [2048,2304) M tiles (16x16 of 32x32), 2304 bias
__global__ __launch_bounds__(256) void prep_kernel(const float* __restrict__ ctx,
                                                   const float* __restrict__ Wq,
                                                   const float* __restrict__ Wk,
                                                   const float* __restrict__ bq,
                                                   const float* __restrict__ bk,
                                                   __bf16* __restrict__ ctx_bf,
                                                   __bf16* __restrict__ m_bf,
                                                   float* __restrict__ avec,
                                                   float* __restrict__ bvec,
                                                   float* __restrict__ c0p) {
    __shared__ float sQ[64 * 32];
    __shared__ float sK[64 * 32];
    __shared__ float red[256];
    const int blk = blockIdx.x;
    const int t = threadIdx.x;

    if (blk < 2048) {
        int i = (blk * 256 + t) * 4;
        const int stride = 2048 * 256 * 4;
        for (; i < MROWS * DD; i += stride) {
            f32x4 v = *(const f32x4*)(ctx + i);
            bf16x4 o;
            o[0] = (__bf16)v[0]; o[1] = (__bf16)v[1];
            o[2] = (__bf16)v[2]; o[3] = (__bf16)v[3];
            *(bf16x4*)(ctx_bf + i) = o;
        }
    } else if (blk < 2304) {
        // M[i,j] = sum_e Wq[e,i] * Wk[e,j]
        const int mb = blk - 2048;
        const int bi = mb >> 4, bj = mb & 15;
        const int ti = t >> 4, tj = t & 15;
        float acc00 = 0.f, acc01 = 0.f, acc10 = 0.f, acc11 = 0.f;
        for (int e0 = 0; e0 < 512; e0 += 64) {
            const int r = t >> 2, c8 = (t & 3) * 8;
            #pragma unroll
            for (int u = 0; u < 2; ++u) {
                f32x4 vq = *(const f32x4*)(Wq + (size_t)(e0 + r) * 512 + bi * 32 + c8 + u * 4);
                f32x4 vk = *(const f32x4*)(Wk + (size_t)(e0 + r) * 512 + bj * 32 + c8 + u * 4);
                *(f32x4*)(sQ + r * 32 + c8 + u * 4) = vq;
                *(f32x4*)(sK + r * 32 + c8 + u * 4) = vk;
            }
            __syncthreads();
            #pragma unroll 8
            for (int e = 0; e < 64; ++e) {
                float q0 = sQ[e * 32 + ti * 2], q1 = sQ[e * 32 + ti * 2 + 1];
                float k0 = sK[e * 32 + tj * 2], k1 = sK[e * 32 + tj * 2 + 1];
                acc00 += q0 * k0; acc01 += q0 * k1;
                acc10 += q1 * k0; acc11 += q1 * k1;
            }
            __syncthreads();
        }
        const int i0 = bi * 32 + ti * 2, j0 = bj * 32 + tj * 2;
        m_bf[(size_t)i0 * 512 + j0]         = (__bf16)acc00;
        m_bf[(size_t)i0 * 512 + j0 + 1]     = (__bf16)acc01;
        m_bf[(size_t)(i0 + 1) * 512 + j0]   = (__bf16)acc10;
        m_bf[(size_t)(i0 + 1) * 512 + j0 + 1] = (__bf16)acc11;
    } else {
        // a = Wq^T bk, b = Wk^T bq, c0 = bq.bk
        #pragma unroll
        for (int h = 0; h < 2; ++h) {
            const int d = t + h * 256;
            float a = 0.f, bv = 0.f;
            for (int e = 0; e < 512; ++e) {
                a  += Wq[(size_t)e * 512 + d] * bk[e];
                bv += Wk[(size_t)e * 512 + d] * bq[e];
            }
            avec[d] = a; bvec[d] = bv;
        }
        red[t] = bq[t] * bk[t] + bq[t + 256] * bk[t + 256];
        __syncthreads();
        for (int off = 128; off > 0; off >>= 1) {
            if (t < off) red[t] += red[t + off];
            __syncthreads();
        }
        if (t == 0) *c0p = red[0];
    }
}

// ============ K2: U = ctx_bf @ M_bf^T  -> fp32 [8192][512] ============
// tile 64(M) x 128(N), BK=32, grid = 128*4 = 512 blocks (bn fastest for A-tile sharing)
__global__ __launch_bounds__(256) void ugemm(const __bf16* __restrict__ A,
                                             const __bf16* __restrict__ Bt,
                                             float* __restrict__ U) {
    __shared__ alignas(16) __bf16 As[64 * 32];
    __shared__ alignas(16) __bf16 Bs[128 * 32];
    const int tid  = threadIdx.x;
    const int lane = tid & 63;
    const int wave = tid >> 6;
    const int wr = wave >> 1, wc = wave & 1;
    const int bm = blockIdx.x >> 2, bn = blockIdx.x & 3;

    f32x4 acc[2][4] = {};
    const int koff = (lane >> 4) * 8;
    const int frow = lane & 15;
    const int row = tid >> 2, kc = (tid & 3) * 8;

    for (int kt = 0; kt < 512; kt += 32) {
        gload_lds16(A + (size_t)(bm * 64 + row) * 512 + kt + kc,
                    (void*)(As + (size_t)wave * 64 * 8));
        #pragma unroll
        for (int ld = 0; ld < 2; ++ld) {
            const int brow = (ld * 256 + tid) >> 2;
            gload_lds16(Bt + (size_t)(bn * 128 + brow) * 512 + kt + kc,
                        (void*)(Bs + (size_t)(ld * 256 + wave * 64) * 8));
        }
        __syncthreads();
        bf16x8 av[2], bv[4];
        #pragma unroll
        for (int m = 0; m < 2; ++m)
            av[m] = *(const bf16x8*)(As + (wr * 32 + m * 16 + frow) * 32 + koff);
        #pragma unroll
        for (int n = 0; n < 4; ++n)
            bv[n] = *(const bf16x8*)(Bs + (wc * 64 + n * 16 + frow) * 32 + koff);
        #pragma unroll
        for (int m = 0; m < 2; ++m)
            #pragma unroll
            for (int n = 0; n < 4; ++n)
                acc[m][n] = __builtin_amdgcn_mfma_f32_16x16x32_bf16(av[m], bv[n], acc[m][n], 0, 0, 0);
        __syncthreads();
    }

    #pragma unroll
    for (int m = 0; m < 2; ++m) {
        const int r0 = bm * 64 + wr * 32 + m * 16 + (lane >> 4) * 4;
        #pragma unroll
        for (int n = 0; n < 4; ++n) {
            const int col = bn * 128 + wc * 64 + n * 16 + frow;
            #pragma unroll
            for (int rg = 0; rg < 4; ++rg)
                U[(size_t)(r0 + rg) * 512 + col] = acc[m][n][rg];
        }
    }
}

// ============ K3: band dots + softmax + per-batch scan (one block per batch) ============
__global__ __launch_bounds__(1024) void band_scan(const float* __restrict__ ctx,
                                                  const float* __restrict__ U,
                                                  const float* __restrict__ avec,
                                                  const float* __restrict__ bvec,
                                                  const float* __restrict__ c0p,
                                                  const int* __restrict__ eos,
                                                  const float* __restrict__ prior,
                                                  float* __restrict__ pp,
                                                  float* __restrict__ pm,
                                                  float* __restrict__ uniV,
                                                  float* __restrict__ Cbuf) {
    __shared__ float shB[1024];   // beta share, then scan buffer
    __shared__ float shP[1024];   // pm share
    const int b = blockIdx.x, s = threadIdx.x;
    const int r = b * SS + s;
    const bool hasP = (s < SS - 1), hasM = (s > 0);
    const int rp = hasP ? r + 1 : r;
    const int rm = hasM ? r - 1 : r;

    const f32x4* cp  = (const f32x4*)(ctx + (size_t)r * DD);
    const f32x4* Up  = (const f32x4*)(U + (size_t)rp * DD);
    const f32x4* Um  = (const f32x4*)(U + (size_t)rm * DD);
    const f32x4* a4  = (const f32x4*)avec;
    const f32x4* b4  = (const f32x4*)bvec;

    f32x4 aP = {}, aM = {}, aA = {}, aB = {};
    for (int d = 0; d < DD / 4; ++d) {
        f32x4 c = cp[d];
        aP += c * Up[d];
        aM += c * Um[d];
        aA += c * a4[d];
        aB += c * b4[d];
    }
    float sp = aP[0] + aP[1] + aP[2] + aP[3];
    float sm = aM[0] + aM[1] + aM[2] + aM[3];
    float al = aA[0] + aA[1] + aA[2] + aA[3];
    float be = aB[0] + aB[1] + aB[2] + aB[3];

    shB[s] = be;
    __syncthreads();
    const float c0 = *c0p;
    const float scp = (sp + al + (hasP ? shB[s + 1] : 0.f) + c0) * (1.f / (float)DD);
    const float scm = (sm + al + (hasM ? shB[s - 1] : 0.f) + c0) * (1.f / (float)DD);

    const bool vp = hasP && (eos[(size_t)b * SS * SS + (size_t)s * SS + (s + 1)] != 0);
    const bool vm = hasM && (eos[(size_t)b * SS * SS + (size_t)s * SS + (s - 1)] != 0);

    float opp, opm, ouni;
    if (!vp && !vm) {
        opp = INV_S; opm = INV_S; ouni = INV_S;
    } else {
        float mx = -3.0e38f;
        if (vp) mx = scp;
        if (vm) mx = fmaxf(mx, scm);
        float ep = vp ? __expf(scp - mx) : 0.f;
        float em = vm ? __expf(scm - mx) : 0.f;
        float inv = 1.f / (ep + em);
        opp = ep * inv; opm = em * inv; ouni = 0.f;
    }
    pp[r] = opp; pm[r] = opm; uniV[r] = ouni;

    shP[s] = opm;
    __syncthreads();
    float Lj = 0.f;
    if (hasP) {
        float pr = prior[(size_t)b * SS * SS + (size_t)s * SS + (s + 1)];
        float prod = opp * shP[s + 1];
        float na = pr + (1.f - pr) * sqrtf(prod + NEG_EPS);
        Lj = __logf(na + NEG_EPS);
    }
    __syncthreads();      // shB beta reads done (before shP barrier), safe to reuse
    shB[s] = Lj;
    __syncthreads();
    for (int off = 1; off < 1024; off <<= 1) {
        float v = (s >= off) ? shB[s - off] : 0.f;
        __syncthreads();
        shB[s] += v;
        __syncthreads();
    }
    Cbuf[r] = (s == 0) ? 0.f : shB[s - 1];   // exclusive prefix
}

// ============ K4: dense fill of both outputs ============
__global__ __launch_bounds__(256) void fill_kernel(const float* __restrict__ prior,
                                                   const float* __restrict__ pp,
                                                   const float* __restrict__ pm,
                                                   const float* __restrict__ uniV,
                                                   const float* __restrict__ Cbuf,
                                                   float* __restrict__ gout,
                                                   float* __restrict__ naout) {
    const int r = blockIdx.x;
    const int b = r >> 10, q = r & 1023;
    const int k0 = threadIdx.x * 4;
    const size_t rowoff = (size_t)r * SS;

    f32x4 pr4 = *(const f32x4*)(prior + rowoff + k0);
    f32x4 uk4 = *(const f32x4*)(uniV + (b << 10) + k0);
    f32x4 C4  = *(const f32x4*)(Cbuf + (b << 10) + k0);
    float uniq = uniV[r];
    float ppq  = pp[r];
    float pmq  = pm[r];
    float Cq   = Cbuf[r];
    float ppp  = (q > 0)      ? pp[r - 1] : 0.f;
    float pmn  = (q < SS - 1) ? pm[r + 1] : 0.f;

    f32x4 g4, na4;
    #pragma unroll
    for (int j = 0; j < 4; ++j) {
        int k = k0 + j;
        float pr = pr4[j];
        float Aqk = (k == q - 1) ? pmq : ((k == q + 1) ? ppq : uniq);
        float Akq = (k == q - 1) ? ppp : ((k == q + 1) ? pmn : uk4[j]);
        float na = pr + (1.f - pr) * sqrtf(Aqk * Akq + NEG_EPS);
        float g;
        if (k == q) {
            g = na;
        } else {
            float dd = (k > q) ? (C4[j] - Cq) : (Cq - C4[j]);
            g = __expf(dd) + NEG_EPS;
        }
        na4[j] = na;
        g4[j]  = g;
    }
    *(f32x4*)(gout + rowoff + k0)  = g4;
    *(f32x4*)(naout + rowoff + k0) = na4;
}

extern "C" void kernel_launch(void* const* d_in, const int* in_sizes, int n_in,
                              void* d_out, int out_size, void* d_ws, size_t ws_size,
                              hipStream_t stream) {
    const float* ctx   = (const float*)d_in[0];
    const int*   eos   = (const int*)d_in[1];
    const float* prior = (const float*)d_in[2];
    const float* Wk    = (const float*)d_in[3];
    const float* bk    = (const float*)d_in[4];
    const float* Wq    = (const float*)d_in[5];
    const float* bq    = (const float*)d_in[6];

    float* gout  = (float*)d_out;
    float* naout = gout + (size_t)BB * SS * SS;

    char* ws = (char*)d_ws;
    __bf16* ctx_bf = (__bf16*)ws;                           // 8 MiB
    __bf16* m_bf   = (__bf16*)(ws + (8u << 20));            // 512 KiB
    float*  U      = (float*)(ws + (9u << 20));             // 16 MiB
    float*  avec   = (float*)(ws + (25u << 20));            // 2 KiB
    float*  bvec   = avec + 512;
    float*  c0p    = bvec + 512;
    float*  ppb    = (float*)(ws + (26u << 20));            // 32 KiB each
    float*  pmb    = ppb + MROWS;
    float*  uniV   = pmb + MROWS;
    float*  Cbuf   = uniV + MROWS;

    prep_kernel<<<2305, 256, 0, stream>>>(ctx, Wq, Wk, bq, bk, ctx_bf, m_bf, avec, bvec, c0p);
    ugemm<<<512, 256, 0, stream>>>(ctx_bf, m_bf, U);
    band_scan<<<BB, 1024, 0, stream>>>(ctx, U, avec, bvec, c0p, eos, prior, ppb, pmb, uniV, Cbuf);
    fill_kernel<<<MROWS, 256, 0, stream>>>(prior, ppb, pmb, uniV, Cbuf, gout, naout);
}

// Round 3
// 179.256 us; speedup vs baseline: 2.3488x; 2.3488x over previous
//
#include <hip/hip_runtime.h>
#include <hip/hip_bf16.h>
#include <stdint.h>

// Problem constants
#define BB 8
#define SS 1024
#define DD 512
#define MROWS (BB*SS)        // 8192
#define NEG_EPS 1e-9f
#define INV_S (1.0f/1024.0f)

typedef __attribute__((ext_vector_type(8))) __bf16 bf16x8;
typedef __attribute__((ext_vector_type(4))) __bf16 bf16x4;
typedef __attribute__((ext_vector_type(4))) float f32x4;

__device__ __forceinline__ void gload_lds16(const void* g, void* l) {
    __builtin_amdgcn_global_load_lds(
        (const __attribute__((address_space(1))) void*)g,
        (__attribute__((address_space(3))) void*)l,
        16, 0, 0);
}

// ============ K1: M = Wq^T @ Wk (bf16) + bias vectors ============
// grid: [0,256) M tiles (16x16 grid of 32x32), [256,272) bias vecs, 272 c0
__global__ __launch_bounds__(256) void prep1(const float* __restrict__ Wq,
                                             const float* __restrict__ Wk,
                                             const float* __restrict__ bq,
                                             const float* __restrict__ bk,
                                             __bf16* __restrict__ m_bf,
                                             float* __restrict__ avec,
                                             float* __restrict__ bvec,
                                             float* __restrict__ c0p) {
    __shared__ float sQ[64 * 32];
    __shared__ float sK[64 * 32];
    __shared__ float red[256];
    __shared__ float sA[8][32];
    __shared__ float sB[8][32];
    const int blk = blockIdx.x;
    const int t = threadIdx.x;

    if (blk < 256) {
        // M[i,j] = sum_e Wq[e,i] * Wk[e,j]
        const int bi = blk >> 4, bj = blk & 15;
        const int ti = t >> 4, tj = t & 15;
        float acc00 = 0.f, acc01 = 0.f, acc10 = 0.f, acc11 = 0.f;
        for (int e0 = 0; e0 < 512; e0 += 64) {
            const int r = t >> 2, c8 = (t & 3) * 8;
            #pragma unroll
            for (int u = 0; u < 2; ++u) {
                f32x4 vq = *(const f32x4*)(Wq + (size_t)(e0 + r) * 512 + bi * 32 + c8 + u * 4);
                f32x4 vk = *(const f32x4*)(Wk + (size_t)(e0 + r) * 512 + bj * 32 + c8 + u * 4);
                *(f32x4*)(sQ + r * 32 + c8 + u * 4) = vq;
                *(f32x4*)(sK + r * 32 + c8 + u * 4) = vk;
            }
            __syncthreads();
            #pragma unroll 8
            for (int e = 0; e < 64; ++e) {
                float q0 = sQ[e * 32 + ti * 2], q1 = sQ[e * 32 + ti * 2 + 1];
                float k0 = sK[e * 32 + tj * 2], k1 = sK[e * 32 + tj * 2 + 1];
                acc00 += q0 * k0; acc01 += q0 * k1;
                acc10 += q1 * k0; acc11 += q1 * k1;
            }
            __syncthreads();
        }
        const int i0 = bi * 32 + ti * 2, j0 = bj * 32 + tj * 2;
        m_bf[(size_t)i0 * 512 + j0]           = (__bf16)acc00;
        m_bf[(size_t)i0 * 512 + j0 + 1]       = (__bf16)acc01;
        m_bf[(size_t)(i0 + 1) * 512 + j0]     = (__bf16)acc10;
        m_bf[(size_t)(i0 + 1) * 512 + j0 + 1] = (__bf16)acc11;
    } else if (blk < 272) {
        // a = Wq^T bk, b = Wk^T bq — 16 blocks x 32 columns, 8 e-groups each
        const int bb = blk - 256;
        const int d  = (t & 31) + bb * 32;
        const int eg = t >> 5;                 // 0..7
        float a = 0.f, bv = 0.f;
        for (int e = eg * 64; e < eg * 64 + 64; ++e) {
            a  += Wq[(size_t)e * 512 + d] * bk[e];
            bv += Wk[(size_t)e * 512 + d] * bq[e];
        }
        sA[eg][t & 31] = a; sB[eg][t & 31] = bv;
        __syncthreads();
        if (t < 32) {
            float sa = 0.f, sb = 0.f;
            #pragma unroll
            for (int g = 0; g < 8; ++g) { sa += sA[g][t]; sb += sB[g][t]; }
            avec[bb * 32 + t] = sa; bvec[bb * 32 + t] = sb;
        }
    } else {
        // c0 = bq . bk
        red[t] = bq[t] * bk[t] + bq[t + 256] * bk[t + 256];
        __syncthreads();
        for (int off = 128; off > 0; off >>= 1) {
            if (t < off) red[t] += red[t + off];
            __syncthreads();
        }
        if (t == 0) *c0p = red[0];
    }
}

// ============ K2: ctx f32 -> bf16 ============
__global__ __launch_bounds__(256) void conv_ctx(const float* __restrict__ src,
                                                __bf16* __restrict__ dst) {
    int i = (blockIdx.x * 256 + threadIdx.x) * 4;
    const int stride = 2048 * 256 * 4;
    for (; i < MROWS * DD; i += stride) {
        f32x4 v = *(const f32x4*)(src + i);
        bf16x4 o;
        o[0] = (__bf16)v[0]; o[1] = (__bf16)v[1];
        o[2] = (__bf16)v[2]; o[3] = (__bf16)v[3];
        *(bf16x4*)(dst + i) = o;
    }
}

// ============ K3: U = ctx_bf @ M_bf^T -> fp32 [8192][512] ============
// tile 64(M) x 128(N), BK=32, grid = 128*4 = 512 blocks
__global__ __launch_bounds__(256) void ugemm(const __bf16* __restrict__ A,
                                             const __bf16* __restrict__ Bt,
                                             float* __restrict__ U) {
    __shared__ alignas(16) __bf16 As[64 * 32];
    __shared__ alignas(16) __bf16 Bs[128 * 32];
    const int tid  = threadIdx.x;
    const int lane = tid & 63;
    const int wave = tid >> 6;
    const int wr = wave >> 1, wc = wave & 1;
    const int bm = blockIdx.x >> 2, bn = blockIdx.x & 3;

    f32x4 acc[2][4] = {};
    const int koff = (lane >> 4) * 8;
    const int frow = lane & 15;
    const int row = tid >> 2, kc = (tid & 3) * 8;

    for (int kt = 0; kt < 512; kt += 32) {
        gload_lds16(A + (size_t)(bm * 64 + row) * 512 + kt + kc,
                    (void*)(As + (size_t)wave * 64 * 8));
        #pragma unroll
        for (int ld = 0; ld < 2; ++ld) {
            const int brow = (ld * 256 + tid) >> 2;
            gload_lds16(Bt + (size_t)(bn * 128 + brow) * 512 + kt + kc,
                        (void*)(Bs + (size_t)(ld * 256 + wave * 64) * 8));
        }
        __syncthreads();
        bf16x8 av[2], bv[4];
        #pragma unroll
        for (int m = 0; m < 2; ++m)
            av[m] = *(const bf16x8*)(As + (wr * 32 + m * 16 + frow) * 32 + koff);
        #pragma unroll
        for (int n = 0; n < 4; ++n)
            bv[n] = *(const bf16x8*)(Bs + (wc * 64 + n * 16 + frow) * 32 + koff);
        #pragma unroll
        for (int m = 0; m < 2; ++m)
            #pragma unroll
            for (int n = 0; n < 4; ++n)
                acc[m][n] = __builtin_amdgcn_mfma_f32_16x16x32_bf16(av[m], bv[n], acc[m][n], 0, 0, 0);
        __syncthreads();
    }

    #pragma unroll
    for (int m = 0; m < 2; ++m) {
        const int r0 = bm * 64 + wr * 32 + m * 16 + (lane >> 4) * 4;
        #pragma unroll
        for (int n = 0; n < 4; ++n) {
            const int col = bn * 128 + wc * 64 + n * 16 + frow;
            #pragma unroll
            for (int rg = 0; rg < 4; ++rg)
                U[(size_t)(r0 + rg) * 512 + col] = acc[m][n][rg];
        }
    }
}

// ============ K4: band scores + 2-way softmax (wave per row, 2048 blocks) ============
__global__ __launch_bounds__(256) void band_kernel(const float* __restrict__ ctx,
                                                   const float* __restrict__ U,
                                                   const float* __restrict__ avec,
                                                   const float* __restrict__ bvec,
                                                   const float* __restrict__ c0p,
                                                   const int* __restrict__ eos,
                                                   float* __restrict__ pp,
                                                   float* __restrict__ pm,
                                                   float* __restrict__ uniV) {
    const int r    = blockIdx.x * 4 + (threadIdx.x >> 6);
    const int lane = threadIdx.x & 63;
    const int b = r >> 10, s = r & 1023;
    const bool hasP = (s < SS - 1), hasM = (s > 0);
    const int rp = hasP ? r + 1 : r;
    const int rm = hasM ? r - 1 : r;

    const f32x4* c4  = (const f32x4*)(ctx + (size_t)r  * DD) + lane * 2;
    const f32x4* cp4 = (const f32x4*)(ctx + (size_t)rp * DD) + lane * 2;
    const f32x4* cm4 = (const f32x4*)(ctx + (size_t)rm * DD) + lane * 2;
    const f32x4* up4 = (const f32x4*)(U   + (size_t)rp * DD) + lane * 2;
    const f32x4* um4 = (const f32x4*)(U   + (size_t)rm * DD) + lane * 2;
    const f32x4* a4  = (const f32x4*)avec + lane * 2;
    const f32x4* b4  = (const f32x4*)bvec + lane * 2;

    // scp_lane = c·(U+ + a) + c+·b ; scm_lane = c·(U- + a) + c-·b
    f32x4 accP = {}, accM = {};
    #pragma unroll
    for (int u = 0; u < 2; ++u) {
        f32x4 c = c4[u], av = a4[u], bv = b4[u];
        accP += c * (up4[u] + av) + cp4[u] * bv;
        accM += c * (um4[u] + av) + cm4[u] * bv;
    }
    float sp = accP[0] + accP[1] + accP[2] + accP[3];
    float sm = accM[0] + accM[1] + accM[2] + accM[3];
    #pragma unroll
    for (int off = 32; off > 0; off >>= 1) {
        sp += __shfl_xor(sp, off);
        sm += __shfl_xor(sm, off);
    }

    if (lane == 0) {
        const float c0 = *c0p;
        const float scp = (sp + c0) * (1.f / (float)DD);
        const float scm = (sm + c0) * (1.f / (float)DD);
        const bool vp = hasP && (eos[(size_t)b * SS * SS + (size_t)s * SS + (s + 1)] != 0);
        const bool vm = hasM && (eos[(size_t)b * SS * SS + (size_t)s * SS + (s - 1)] != 0);
        float opp, opm, ouni;
        if (!vp && !vm) {
            opp = INV_S; opm = INV_S; ouni = INV_S;
        } else {
            float mx = -3.0e38f;
            if (vp) mx = scp;
            if (vm) mx = fmaxf(mx, scm);
            float ep = vp ? __expf(scp - mx) : 0.f;
            float em = vm ? __expf(scm - mx) : 0.f;
            float inv = 1.f / (ep + em);
            opp = ep * inv; opm = em * inv; ouni = 0.f;
        }
        pp[r] = opp; pm[r] = opm; uniV[r] = ouni;
    }
}

// ============ K5: per-batch scan of L = log(na_band + eps) ============
__global__ __launch_bounds__(1024) void scan_kernel(const float* __restrict__ prior,
                                                    const float* __restrict__ pp,
                                                    const float* __restrict__ pm,
                                                    float* __restrict__ Cbuf) {
    int b = blockIdx.x;
    int j = threadIdx.x;
    __shared__ float sb[1024];
    float Lj = 0.f;
    if (j < SS - 1) {
        float pr = prior[((size_t)b * SS + j) * SS + (j + 1)];
        float prod = pp[b * SS + j] * pm[b * SS + j + 1];
        float na = pr + (1.f - pr) * sqrtf(prod + NEG_EPS);
        Lj = __logf(na + NEG_EPS);
    }
    sb[j] = Lj;
    __syncthreads();
    for (int off = 1; off < 1024; off <<= 1) {
        float v = (j >= off) ? sb[j - off] : 0.f;
        __syncthreads();
        sb[j] += v;
        __syncthreads();
    }
    Cbuf[b * SS + j] = (j == 0) ? 0.f : sb[j - 1];   // exclusive prefix
}

// ============ K6: dense fill of both outputs ============
__global__ __launch_bounds__(256) void fill_kernel(const float* __restrict__ prior,
                                                   const float* __restrict__ pp,
                                                   const float* __restrict__ pm,
                                                   const float* __restrict__ uniV,
                                                   const float* __restrict__ Cbuf,
                                                   float* __restrict__ gout,
                                                   float* __restrict__ naout) {
    const int r = blockIdx.x;
    const int b = r >> 10, q = r & 1023;
    const int k0 = threadIdx.x * 4;
    const size_t rowoff = (size_t)r * SS;

    f32x4 pr4 = *(const f32x4*)(prior + rowoff + k0);
    f32x4 uk4 = *(const f32x4*)(uniV + (b << 10) + k0);
    f32x4 C4  = *(const f32x4*)(Cbuf + (b << 10) + k0);
    float uniq = uniV[r];
    float ppq  = pp[r];
    float pmq  = pm[r];
    float Cq   = Cbuf[r];
    float ppp  = (q > 0)      ? pp[r - 1] : 0.f;
    float pmn  = (q < SS - 1) ? pm[r + 1] : 0.f;

    f32x4 g4, na4;
    #pragma unroll
    for (int j = 0; j < 4; ++j) {
        int k = k0 + j;
        float pr = pr4[j];
        float Aqk = (k == q - 1) ? pmq : ((k == q + 1) ? ppq : uniq);
        float Akq = (k == q - 1) ? ppp : ((k == q + 1) ? pmn : uk4[j]);
        float na = pr + (1.f - pr) * sqrtf(Aqk * Akq + NEG_EPS);
        float g;
        if (k == q) {
            g = na;
        } else {
            float dd = (k > q) ? (C4[j] - Cq) : (Cq - C4[j]);
            g = __expf(dd) + NEG_EPS;
        }
        na4[j] = na;
        g4[j]  = g;
    }
    *(f32x4*)(gout + rowoff + k0)  = g4;
    *(f32x4*)(naout + rowoff + k0) = na4;
}

extern "C" void kernel_launch(void* const* d_in, const int* in_sizes, int n_in,
                              void* d_out, int out_size, void* d_ws, size_t ws_size,
                              hipStream_t stream) {
    const float* ctx   = (const float*)d_in[0];
    const int*   eos   = (const int*)d_in[1];
    const float* prior = (const float*)d_in[2];
    const float* Wk    = (const float*)d_in[3];
    const float* bk    = (const float*)d_in[4];
    const float* Wq    = (const float*)d_in[5];
    const float* bq    = (const float*)d_in[6];

    float* gout  = (float*)d_out;
    float* naout = gout + (size_t)BB * SS * SS;

    char* ws = (char*)d_ws;
    __bf16* ctx_bf = (__bf16*)ws;                           // 8 MiB
    __bf16* m_bf   = (__bf16*)(ws + (8u << 20));            // 512 KiB
    float*  U      = (float*)(ws + (9u << 20));             // 16 MiB
    float*  avec   = (float*)(ws + (25u << 20));            // 2 KiB
    float*  bvec   = avec + 512;
    float*  c0p    = bvec + 512;
    float*  ppb    = (float*)(ws + (26u << 20));            // 32 KiB each
    float*  pmb    = ppb + MROWS;
    float*  uniV   = pmb + MROWS;
    float*  Cbuf   = uniV + MROWS;

    prep1<<<273, 256, 0, stream>>>(Wq, Wk, bq, bk, m_bf, avec, bvec, c0p);
    conv_ctx<<<2048, 256, 0, stream>>>(ctx, ctx_bf);
    ugemm<<<512, 256, 0, stream>>>(ctx_bf, m_bf, U);
    band_kernel<<<MROWS / 4, 256, 0, stream>>>(ctx, U, avec, bvec, c0p, eos, ppb, pmb, uniV);
    scan_kernel<<<BB, 1024, 0, stream>>>(prior, ppb, pmb, Cbuf);
    fill_kernel<<<MROWS, 256, 0, stream>>>(prior, ppb, pmb, uniV, Cbuf, gout, naout);
}